// Round 3
// baseline (869.528 us; speedup 1.0000x reference)
//
#include <hip/hip_runtime.h>

#define DD 128

typedef __attribute__((ext_vector_type(8))) short short8;
typedef __attribute__((ext_vector_type(4))) float f32x4;

__device__ inline unsigned short f2bf(float f) {
    unsigned u = __float_as_uint(f);
    unsigned r = (u + 0x7fffu + ((u >> 16) & 1u)) >> 16;
    return (unsigned short)r;
}
__device__ inline float bf2f(unsigned short u) {
    return __uint_as_float(((unsigned)u) << 16);
}
__device__ inline unsigned pack2(float a, float b) {
    return (unsigned)f2bf(a) | ((unsigned)f2bf(b) << 16);
}

// ---------------- fp32 -> bf16 convert ----------------
__global__ __launch_bounds__(256) void conv_bf16(const float* __restrict__ in,
                                                 unsigned short* __restrict__ out, int n4) {
    int i = blockIdx.x * blockDim.x + threadIdx.x;
    if (i >= n4) return;
    float4 v = *(const float4*)(in + (size_t)i * 4);
    uint2 o;
    o.x = pack2(v.x, v.y);
    o.y = pack2(v.z, v.w);
    *(uint2*)(out + (size_t)i * 4) = o;
}

// ---------------- weight pack: fragment-order bf16 B for mfma_f32_16x16x32_bf16 ----------------
// Bpack[((t*ktiles + kk)*64 + lane)*8 + j] = Wcat[n][k], n = t*16 + (lane&15), k = kk*32 + (lane>>4)*8 + j
__global__ void pack_w(const float* __restrict__ W1, const float* __restrict__ W2,
                       short* __restrict__ dst, int ktiles) {
    int idx = blockIdx.x * blockDim.x + threadIdx.x;
    int total = 8 * ktiles * 64;
    if (idx >= total) return;
    int lane = idx & 63;
    int kk = (idx >> 6) % ktiles;
    int t = (idx >> 6) / ktiles;
    int n = t * 16 + (lane & 15);
    int kbase = kk * 32 + (lane >> 4) * 8;
    short8 v;
#pragma unroll
    for (int j = 0; j < 8; ++j) {
        int k = kbase + j;
        float f = (k < 128) ? W1[n * 128 + k] : W2[n * 128 + (k - 128)];
        v[j] = (short)f2bf(f);
    }
    *(short8*)(dst + (size_t)idx * 8) = v;
}

// ---------------- CSR build ----------------
__global__ __launch_bounds__(256) void count_main(const int* __restrict__ aidx,
                                                  const int* __restrict__ pidx,
                                                  int* __restrict__ cntP, int* __restrict__ cntA, int E) {
    int e = blockIdx.x * blockDim.x + threadIdx.x;
    if (e >= E) return;
    atomicAdd(&cntP[pidx[e]], 1);
    atomicAdd(&cntA[aidx[e]], 1);
}

__global__ __launch_bounds__(256) void count_co(const int* __restrict__ dst, int* __restrict__ cntC, int E) {
    int e = blockIdx.x * blockDim.x + threadIdx.x;
    if (e >= E) return;
    atomicAdd(&cntC[dst[e]], 1);
}

__global__ __launch_bounds__(256) void scan_local(const int* __restrict__ cnt, int* __restrict__ row,
                                                  int* __restrict__ partials, int N) {
    __shared__ int sh[256];
    int t = threadIdx.x;
    int base = blockIdx.x * 1024 + t * 4;
    int v0 = 0, v1 = 0, v2 = 0, v3 = 0;
    if (base + 0 < N) v0 = cnt[base + 0];
    if (base + 1 < N) v1 = cnt[base + 1];
    if (base + 2 < N) v2 = cnt[base + 2];
    if (base + 3 < N) v3 = cnt[base + 3];
    sh[t] = v0 + v1 + v2 + v3;
    __syncthreads();
    for (int off = 1; off < 256; off <<= 1) {
        int y = (t >= off) ? sh[t - off] : 0;
        __syncthreads();
        sh[t] += y;
        __syncthreads();
    }
    int excl = (t > 0) ? sh[t - 1] : 0;
    if (t == 255) partials[blockIdx.x] = sh[255];
    if (base + 0 < N) row[base + 0] = excl; excl += v0;
    if (base + 1 < N) row[base + 1] = excl; excl += v1;
    if (base + 2 < N) row[base + 2] = excl; excl += v2;
    if (base + 3 < N) row[base + 3] = excl;
}

__global__ __launch_bounds__(256) void scan_partials(int* __restrict__ partials, int nb) {
    __shared__ int sh[256];
    int t = threadIdx.x;
    int v = (t < nb) ? partials[t] : 0;
    sh[t] = v;
    __syncthreads();
    for (int off = 1; off < 256; off <<= 1) {
        int y = (t >= off) ? sh[t - off] : 0;
        __syncthreads();
        sh[t] += y;
        __syncthreads();
    }
    if (t < nb) partials[t] = (t > 0) ? sh[t - 1] : 0;
}

__global__ __launch_bounds__(256) void scan_finalize(int* __restrict__ row, int* __restrict__ cur,
                                                     const int* __restrict__ partials, int N) {
    int i = blockIdx.x * blockDim.x + threadIdx.x;
    if (i >= N) return;
    int r = row[i] + partials[i >> 10];
    row[i] = r;
    cur[i] = r;
}

__global__ __launch_bounds__(256) void fill_main(const int* __restrict__ aidx, const int* __restrict__ pidx,
                                                 int* __restrict__ curP, int* __restrict__ curA,
                                                 int* __restrict__ adjP, int* __restrict__ adjA, int E) {
    int e = blockIdx.x * blockDim.x + threadIdx.x;
    if (e >= E) return;
    int a = aidx[e], p = pidx[e];
    adjP[atomicAdd(&curP[p], 1)] = a;
    adjA[atomicAdd(&curA[a], 1)] = p;
}

__global__ __launch_bounds__(256) void fill_co(const int* __restrict__ src, const int* __restrict__ dst,
                                               int* __restrict__ curC, int* __restrict__ adjC, int E) {
    int e = blockIdx.x * blockDim.x + threadIdx.x;
    if (e >= E) return;
    adjC[atomicAdd(&curC[dst[e]], 1)] = src[e];
}

// ---------------- fused gather + transform ----------------
// out[node] = (sum_{s in adj[node]} gsrc[s]) @ W1.T  (+ selfx[node] @ W2.T)  + cnt*b1 (+ b2) (+ base)
// KTILES=8: K=256, A = [agg | self] both staged in LDS.  KTILES=4: K=128, agg only.
template <int KTILES, bool HAS_B2, bool ADD_BASE>
__global__ __launch_bounds__(256) void fused_kernel(
    const unsigned short* __restrict__ gsrc, const unsigned short* __restrict__ selfx,
    const unsigned short* __restrict__ base,
    const int* __restrict__ adj, const int* __restrict__ rowp, const int* __restrict__ cnt,
    const short* __restrict__ Bpack,
    const float* __restrict__ b1, const float* __restrict__ b2,
    unsigned short* __restrict__ out, int M) {
    constexpr int STRB = KTILES * 64;  // LDS bytes per row (8 -> 512, 4 -> 256)
    __shared__ char lds[64 * STRB];

    const int tid = threadIdx.x;
    const int node0 = blockIdx.x * 64;

    // phase A1: gather neighbor sums -> LDS cols [0,256) bytes (128 bf16)
    {
        const int grp = tid >> 5;  // 8 groups of 32 lanes
        const int l = tid & 31;
#pragma unroll
        for (int i = 0; i < 8; ++i) {
            int lr = grp * 8 + i;
            int node = node0 + lr;
            float a0 = 0.f, a1 = 0.f, a2 = 0.f, a3 = 0.f;
            if (node < M) {
                int st = rowp[node], d = cnt[node];
                for (int k = 0; k < d; ++k) {
                    int s = adj[st + k];
                    uint2 v = *(const uint2*)(gsrc + (size_t)s * DD + l * 4);
                    a0 += bf2f((unsigned short)(v.x & 0xffff));
                    a1 += bf2f((unsigned short)(v.x >> 16));
                    a2 += bf2f((unsigned short)(v.y & 0xffff));
                    a3 += bf2f((unsigned short)(v.y >> 16));
                }
            }
            uint2 o;
            o.x = pack2(a0, a1);
            o.y = pack2(a2, a3);
            int colb = l * 8;
            *(uint2*)(lds + lr * STRB + (colb ^ ((lr & 7) << 4))) = o;
        }
    }
    // phase A2: stage self rows -> LDS cols [256,512) bytes
    if (KTILES == 8) {
        const int l = tid & 31;
        const int r0 = tid >> 5;
#pragma unroll
        for (int p = 0; p < 8; ++p) {
            int lr = r0 + p * 8;
            int node = node0 + lr;
            if (node >= M) node = M - 1;
            uint2 v = *(const uint2*)(selfx + (size_t)node * DD + l * 4);
            int colb = 256 + l * 8;
            *(uint2*)(lds + lr * STRB + (colb ^ ((lr & 7) << 4))) = v;
        }
    }
    __syncthreads();

    // phase B: MFMA
    const int wave = tid >> 6;
    const int lane = tid & 63;
    const int kg = lane >> 4;
    const int lrA = wave * 16 + (lane & 15);

    f32x4 acc[8];
#pragma unroll
    for (int t = 0; t < 8; ++t) acc[t] = (f32x4){0.f, 0.f, 0.f, 0.f};

#pragma unroll
    for (int kk = 0; kk < KTILES; ++kk) {
        int colb = kk * 64 + kg * 16;
        short8 af = *(const short8*)(lds + lrA * STRB + (colb ^ ((lrA & 7) << 4)));
#pragma unroll
        for (int t = 0; t < 8; ++t) {
            short8 bf = *(const short8*)(Bpack + ((size_t)(t * KTILES + kk) * 64 + lane) * 8);
            acc[t] = __builtin_amdgcn_mfma_f32_16x16x32_bf16(af, bf, acc[t], 0, 0, 0);
        }
    }

    // epilogue
    const int col0 = lane & 15;
    const int crow0 = node0 + wave * 16 + kg * 4;
#pragma unroll
    for (int t = 0; t < 8; ++t) {
        int col = t * 16 + col0;
        float bb = b1[col];
        float b2v = HAS_B2 ? b2[col] : 0.f;
#pragma unroll
        for (int r = 0; r < 4; ++r) {
            int row = crow0 + r;
            if (row < M) {
                float v = acc[t][r] + (float)cnt[row] * bb + b2v;
                if (ADD_BASE) v += bf2f(base[(size_t)row * DD + col]);
                out[(size_t)row * DD + col] = f2bf(v);
            }
        }
    }
}

// ---------------- supervision dot (bf16 inputs, fp32 out) ----------------
__global__ __launch_bounds__(256) void dot_kernel(
    const unsigned short* __restrict__ xa, const unsigned short* __restrict__ xp,
    const int* __restrict__ s0, const int* __restrict__ s1,
    float* __restrict__ out, int E) {
    int g = blockIdx.x * blockDim.x + threadIdx.x;
    int e = g >> 5;
    int l = g & 31;
    if (e >= E) return;
    int a = s0[e], p = s1[e];
    uint2 va = *(const uint2*)(xa + (size_t)a * DD + l * 4);
    uint2 vp = *(const uint2*)(xp + (size_t)p * DD + l * 4);
    float s = bf2f((unsigned short)(va.x & 0xffff)) * bf2f((unsigned short)(vp.x & 0xffff))
            + bf2f((unsigned short)(va.x >> 16)) * bf2f((unsigned short)(vp.x >> 16))
            + bf2f((unsigned short)(va.y & 0xffff)) * bf2f((unsigned short)(vp.y & 0xffff))
            + bf2f((unsigned short)(va.y >> 16)) * bf2f((unsigned short)(vp.y >> 16));
    s += __shfl_xor(s, 1); s += __shfl_xor(s, 2); s += __shfl_xor(s, 4);
    s += __shfl_xor(s, 8); s += __shfl_xor(s, 16);
    if (l == 0) out[e] = s;
}

extern "C" void kernel_launch(void* const* d_in, const int* in_sizes, int n_in,
                              void* d_out, int out_size, void* d_ws, size_t ws_size,
                              hipStream_t stream) {
    const float* xa_in = (const float*)d_in[0];
    const float* xp_in = (const float*)d_in[1];
    const int* eidx = (const int*)d_in[2];
    const int* co = (const int*)d_in[3];
    const int* sup = (const int*)d_in[4];
    const float* W_a2p = (const float*)d_in[5];
    const float* b_a2p = (const float*)d_in[6];
    const float* W_p2a = (const float*)d_in[7];
    const float* b_p2a = (const float*)d_in[8];
    const float* W_aself = (const float*)d_in[9];
    const float* b_aself = (const float*)d_in[10];
    const float* W_pself = (const float*)d_in[11];
    const float* b_pself = (const float*)d_in[12];
    const float* W_co = (const float*)d_in[13];
    const float* b_co = (const float*)d_in[14];

    const int NA = in_sizes[0] / DD;
    const int NP = in_sizes[1] / DD;
    const int E = in_sizes[2] / 2;
    const int Eco = in_sizes[3] / 2;
    const int Esup = in_sizes[4] / 2;
    const int* a_idx = eidx;
    const int* p_idx = eidx + E;
    const int* co_s = co;
    const int* co_d = co + Eco;
    const int* s0 = sup;
    const int* s1 = sup + Esup;

    char* w = (char*)d_ws;
    auto carve = [&](size_t bytes) -> char* {
        char* p = w;
        w += (bytes + 255) & ~(size_t)255;
        return p;
    };
    unsigned short* XA = (unsigned short*)carve((size_t)NA * DD * 2);
    unsigned short* XP = (unsigned short*)carve((size_t)NP * DD * 2);
    unsigned short* P0b = (unsigned short*)carve((size_t)NP * DD * 2);  // paper L1 out
    unsigned short* P1b = (unsigned short*)carve((size_t)NP * DD * 2);  // paper L2 out
    unsigned short* A0b = (unsigned short*)carve((size_t)NA * DD * 2);  // author scratch
    unsigned short* A1b = (unsigned short*)carve((size_t)NA * DD * 2);  // author final per layer
    int* cntP = (int*)carve((size_t)NP * 4);
    int* rowP = (int*)carve((size_t)NP * 4);
    int* curP = (int*)carve((size_t)NP * 4);
    int* cntA = (int*)carve((size_t)NA * 4);
    int* rowA = (int*)carve((size_t)NA * 4);
    int* curA = (int*)carve((size_t)NA * 4);
    int* cntC = (int*)carve((size_t)NA * 4);
    int* rowC = (int*)carve((size_t)NA * 4);
    int* curC = (int*)carve((size_t)NA * 4);
    int* adjP = (int*)carve((size_t)E * 4);
    int* adjA = (int*)carve((size_t)E * 4);
    int* adjC = (int*)carve((size_t)Eco * 4);
    int* partP = (int*)carve(256 * 4);
    int* partA = (int*)carve(256 * 4);
    int* partC = (int*)carve(256 * 4);
    short* BPp0 = (short*)carve(8 * 8 * 64 * 8 * 2);
    short* BPp1 = (short*)carve(8 * 8 * 64 * 8 * 2);
    short* BPa0 = (short*)carve(8 * 8 * 64 * 8 * 2);
    short* BPa1 = (short*)carve(8 * 8 * 64 * 8 * 2);
    short* BPc0 = (short*)carve(8 * 4 * 64 * 8 * 2);
    short* BPc1 = (short*)carve(8 * 4 * 64 * 8 * 2);

    const int WL = 128 * 128;
    conv_bf16<<<(NA * DD / 4 + 255) / 256, 256, 0, stream>>>(xa_in, XA, NA * DD / 4);
    conv_bf16<<<(NP * DD / 4 + 255) / 256, 256, 0, stream>>>(xp_in, XP, NP * DD / 4);
    pack_w<<<16, 256, 0, stream>>>(W_a2p, W_pself, BPp0, 8);
    pack_w<<<16, 256, 0, stream>>>(W_a2p + WL, W_pself + WL, BPp1, 8);
    pack_w<<<16, 256, 0, stream>>>(W_p2a, W_aself, BPa0, 8);
    pack_w<<<16, 256, 0, stream>>>(W_p2a + WL, W_aself + WL, BPa1, 8);
    pack_w<<<8, 256, 0, stream>>>(W_co, nullptr, BPc0, 4);
    pack_w<<<8, 256, 0, stream>>>(W_co + WL, nullptr, BPc1, 4);

    // ---- CSR build (once; reused for both layers) ----
    hipMemsetAsync(cntP, 0, (size_t)NP * 4, stream);
    hipMemsetAsync(cntA, 0, (size_t)NA * 4, stream);
    hipMemsetAsync(cntC, 0, (size_t)NA * 4, stream);
    count_main<<<(E + 255) / 256, 256, 0, stream>>>(a_idx, p_idx, cntP, cntA, E);
    count_co<<<(Eco + 255) / 256, 256, 0, stream>>>(co_d, cntC, Eco);
    const int nbP = (NP + 1023) / 1024;
    const int nbA = (NA + 1023) / 1024;
    scan_local<<<nbP, 256, 0, stream>>>(cntP, rowP, partP, NP);
    scan_partials<<<1, 256, 0, stream>>>(partP, nbP);
    scan_finalize<<<(NP + 255) / 256, 256, 0, stream>>>(rowP, curP, partP, NP);
    scan_local<<<nbA, 256, 0, stream>>>(cntA, rowA, partA, NA);
    scan_partials<<<1, 256, 0, stream>>>(partA, nbA);
    scan_finalize<<<(NA + 255) / 256, 256, 0, stream>>>(rowA, curA, partA, NA);
    scan_local<<<nbA, 256, 0, stream>>>(cntC, rowC, partC, NA);
    scan_partials<<<1, 256, 0, stream>>>(partC, nbA);
    scan_finalize<<<(NA + 255) / 256, 256, 0, stream>>>(rowC, curC, partC, NA);
    fill_main<<<(E + 255) / 256, 256, 0, stream>>>(a_idx, p_idx, curP, curA, adjP, adjA, E);
    fill_co<<<(Eco + 255) / 256, 256, 0, stream>>>(co_s, co_d, curC, adjC, Eco);

    const int blkP = (NP + 63) / 64;
    const int blkA = (NA + 63) / 64;

    // ---- Layer 1 ----
    fused_kernel<8, true, false><<<blkP, 256, 0, stream>>>(XA, XP, nullptr, adjP, rowP, cntP, BPp0, b_a2p, b_pself, P0b, NP);
    fused_kernel<8, true, false><<<blkA, 256, 0, stream>>>(XP, XA, nullptr, adjA, rowA, cntA, BPa0, b_p2a, b_aself, A0b, NA);
    fused_kernel<4, false, true><<<blkA, 256, 0, stream>>>(A0b, nullptr, A0b, adjC, rowC, cntC, BPc0, b_co, nullptr, A1b, NA);

    // ---- Layer 2 ----
    fused_kernel<8, true, false><<<blkP, 256, 0, stream>>>(A1b, P0b, nullptr, adjP, rowP, cntP, BPp1, b_a2p + 128, b_pself + 128, P1b, NP);
    fused_kernel<8, true, false><<<blkA, 256, 0, stream>>>(P0b, A1b, nullptr, adjA, rowA, cntA, BPa1, b_p2a + 128, b_aself + 128, A0b, NA);
    fused_kernel<4, false, true><<<blkA, 256, 0, stream>>>(A0b, nullptr, A0b, adjC, rowC, cntC, BPc1, b_co + 128, nullptr, A1b, NA);

    // ---- output ----
    dot_kernel<<<(Esup * 32 + 255) / 256, 256, 0, stream>>>(A1b, P1b, s0, s1, (float*)d_out, Esup);
}

// Round 4
// 639.860 us; speedup vs baseline: 1.3589x; 1.3589x over previous
//
#include <hip/hip_runtime.h>

#define DD 128

typedef __attribute__((ext_vector_type(8))) short short8;
typedef __attribute__((ext_vector_type(4))) float f32x4;

__device__ inline unsigned short f2bf(float f) {
    unsigned u = __float_as_uint(f);
    unsigned r = (u + 0x7fffu + ((u >> 16) & 1u)) >> 16;
    return (unsigned short)r;
}
__device__ inline float bf2f(unsigned short u) {
    return __uint_as_float(((unsigned)u) << 16);
}
__device__ inline unsigned pack2(float a, float b) {
    return (unsigned)f2bf(a) | ((unsigned)f2bf(b) << 16);
}

// ---------------- fp32 -> bf16 convert ----------------
__global__ __launch_bounds__(256) void conv_bf16(const float* __restrict__ in,
                                                 unsigned short* __restrict__ out, int n4) {
    int i = blockIdx.x * blockDim.x + threadIdx.x;
    if (i >= n4) return;
    float4 v = *(const float4*)(in + (size_t)i * 4);
    uint2 o;
    o.x = pack2(v.x, v.y);
    o.y = pack2(v.z, v.w);
    *(uint2*)(out + (size_t)i * 4) = o;
}

// ---------------- weight pack: fragment-order bf16 B for mfma_f32_16x16x32_bf16 ----------------
__global__ void pack_w(const float* __restrict__ W1, const float* __restrict__ W2,
                       short* __restrict__ dst, int ktiles) {
    int idx = blockIdx.x * blockDim.x + threadIdx.x;
    int total = 8 * ktiles * 64;
    if (idx >= total) return;
    int lane = idx & 63;
    int kk = (idx >> 6) % ktiles;
    int t = (idx >> 6) / ktiles;
    int n = t * 16 + (lane & 15);
    int kbase = kk * 32 + (lane >> 4) * 8;
    short8 v;
#pragma unroll
    for (int j = 0; j < 8; ++j) {
        int k = kbase + j;
        float f = (k < 128) ? W1[n * 128 + k] : W2[n * 128 + (k - 128)];
        v[j] = (short)f2bf(f);
    }
    *(short8*)(dst + (size_t)idx * 8) = v;
}

// ---------------- CSR build ----------------
__global__ __launch_bounds__(256) void count_main(const int* __restrict__ aidx,
                                                  const int* __restrict__ pidx,
                                                  int* __restrict__ cntP, int* __restrict__ cntA, int E) {
    int e = blockIdx.x * blockDim.x + threadIdx.x;
    if (e >= E) return;
    atomicAdd(&cntP[pidx[e]], 1);
    atomicAdd(&cntA[aidx[e]], 1);
}

__global__ __launch_bounds__(256) void count_co(const int* __restrict__ dst, int* __restrict__ cntC, int E) {
    int e = blockIdx.x * blockDim.x + threadIdx.x;
    if (e >= E) return;
    atomicAdd(&cntC[dst[e]], 1);
}

__global__ __launch_bounds__(256) void scan_local(const int* __restrict__ cnt, int* __restrict__ row,
                                                  int* __restrict__ partials, int N) {
    __shared__ int sh[256];
    int t = threadIdx.x;
    int base = blockIdx.x * 1024 + t * 4;
    int v0 = 0, v1 = 0, v2 = 0, v3 = 0;
    if (base + 0 < N) v0 = cnt[base + 0];
    if (base + 1 < N) v1 = cnt[base + 1];
    if (base + 2 < N) v2 = cnt[base + 2];
    if (base + 3 < N) v3 = cnt[base + 3];
    sh[t] = v0 + v1 + v2 + v3;
    __syncthreads();
    for (int off = 1; off < 256; off <<= 1) {
        int y = (t >= off) ? sh[t - off] : 0;
        __syncthreads();
        sh[t] += y;
        __syncthreads();
    }
    int excl = (t > 0) ? sh[t - 1] : 0;
    if (t == 255) partials[blockIdx.x] = sh[255];
    if (base + 0 < N) row[base + 0] = excl; excl += v0;
    if (base + 1 < N) row[base + 1] = excl; excl += v1;
    if (base + 2 < N) row[base + 2] = excl; excl += v2;
    if (base + 3 < N) row[base + 3] = excl;
}

__global__ __launch_bounds__(256) void scan_partials(int* __restrict__ partials, int nb) {
    __shared__ int sh[256];
    int t = threadIdx.x;
    int v = (t < nb) ? partials[t] : 0;
    sh[t] = v;
    __syncthreads();
    for (int off = 1; off < 256; off <<= 1) {
        int y = (t >= off) ? sh[t - off] : 0;
        __syncthreads();
        sh[t] += y;
        __syncthreads();
    }
    if (t < nb) partials[t] = (t > 0) ? sh[t - 1] : 0;
}

__global__ __launch_bounds__(256) void scan_finalize(int* __restrict__ row, int* __restrict__ cur,
                                                     const int* __restrict__ partials, int N) {
    int i = blockIdx.x * blockDim.x + threadIdx.x;
    if (i >= N) return;
    int r = row[i] + partials[i >> 10];
    row[i] = r;
    cur[i] = r;
}

__global__ __launch_bounds__(256) void fill_main(const int* __restrict__ aidx, const int* __restrict__ pidx,
                                                 int* __restrict__ curP, int* __restrict__ curA,
                                                 int* __restrict__ adjP, int* __restrict__ adjA, int E) {
    int e = blockIdx.x * blockDim.x + threadIdx.x;
    if (e >= E) return;
    int a = aidx[e], p = pidx[e];
    adjP[atomicAdd(&curP[p], 1)] = a;
    adjA[atomicAdd(&curA[a], 1)] = p;
}

__global__ __launch_bounds__(256) void fill_co(const int* __restrict__ src, const int* __restrict__ dst,
                                               int* __restrict__ curC, int* __restrict__ adjC, int E) {
    int e = blockIdx.x * blockDim.x + threadIdx.x;
    if (e >= E) return;
    adjC[atomicAdd(&curC[dst[e]], 1)] = src[e];
}

// ---------------- fused gather + transform ----------------
// out[node] = (sum_{s in adj[node]} gsrc[s]) @ W1.T (+ selfx[node] @ W2.T) + cnt*b1 (+ b2) (+ base)
template <int KTILES, bool HAS_B2, bool ADD_BASE>
__global__ __launch_bounds__(256, 4) void fused_kernel(
    const unsigned short* __restrict__ gsrc, const unsigned short* __restrict__ selfx,
    const unsigned short* __restrict__ base,
    const int* __restrict__ adj, const int* __restrict__ rowp, const int* __restrict__ cnt,
    const short* __restrict__ Bpack,
    const float* __restrict__ b1, const float* __restrict__ b2,
    unsigned short* __restrict__ out, int M) {
    constexpr int STRB = KTILES * 64;
    __shared__ char lds[64 * STRB];

    const int tid = threadIdx.x;
    const int node0 = blockIdx.x * 64;
    const int grp = tid >> 5;
    const int l = tid & 31;

    // row metadata for this group's 8 rows (independent loads, issued together)
    int stA[8], dA[8];
#pragma unroll
    for (int i = 0; i < 8; ++i) {
        int node = node0 + grp * 8 + i;
        bool ok = node < M;
        stA[i] = ok ? rowp[node] : 0;
        dA[i] = ok ? cnt[node] : 0;
    }

    // pre-issue self-row loads so they overlap the gather latency
    uint2 selfv[8];
    if (KTILES == 8) {
#pragma unroll
        for (int p = 0; p < 8; ++p) {
            int node = node0 + grp + p * 8;
            if (node >= M) node = M - 1;
            selfv[p] = *(const uint2*)(selfx + (size_t)node * DD + l * 4);
        }
    }

    // gather: chunk-of-4 over all 8 rows per step -> up to 32 loads in flight
    float acc[8][4];
#pragma unroll
    for (int i = 0; i < 8; ++i) { acc[i][0] = acc[i][1] = acc[i][2] = acc[i][3] = 0.f; }
    int dmax = dA[0];
#pragma unroll
    for (int i = 1; i < 8; ++i) dmax = dA[i] > dmax ? dA[i] : dmax;

    for (int k = 0; k < dmax; k += 4) {
#pragma unroll
        for (int i = 0; i < 8; ++i) {
            if (k < dA[i]) {
                int st = stA[i] + k;
                int rem = dA[i] - k;
                int s0 = adj[st];
                int s1 = adj[st + ((rem > 1) ? 1 : 0)];
                int s2 = adj[st + ((rem > 2) ? 2 : 0)];
                int s3 = adj[st + ((rem > 3) ? 3 : 0)];
                float w1 = (rem > 1) ? 1.f : 0.f;
                float w2 = (rem > 2) ? 1.f : 0.f;
                float w3 = (rem > 3) ? 1.f : 0.f;
                uint2 v0 = *(const uint2*)(gsrc + (size_t)s0 * DD + l * 4);
                uint2 v1 = *(const uint2*)(gsrc + (size_t)s1 * DD + l * 4);
                uint2 v2 = *(const uint2*)(gsrc + (size_t)s2 * DD + l * 4);
                uint2 v3 = *(const uint2*)(gsrc + (size_t)s3 * DD + l * 4);
                acc[i][0] += bf2f((unsigned short)(v0.x & 0xffff));
                acc[i][1] += bf2f((unsigned short)(v0.x >> 16));
                acc[i][2] += bf2f((unsigned short)(v0.y & 0xffff));
                acc[i][3] += bf2f((unsigned short)(v0.y >> 16));
                acc[i][0] += w1 * bf2f((unsigned short)(v1.x & 0xffff));
                acc[i][1] += w1 * bf2f((unsigned short)(v1.x >> 16));
                acc[i][2] += w1 * bf2f((unsigned short)(v1.y & 0xffff));
                acc[i][3] += w1 * bf2f((unsigned short)(v1.y >> 16));
                acc[i][0] += w2 * bf2f((unsigned short)(v2.x & 0xffff));
                acc[i][1] += w2 * bf2f((unsigned short)(v2.x >> 16));
                acc[i][2] += w2 * bf2f((unsigned short)(v2.y & 0xffff));
                acc[i][3] += w2 * bf2f((unsigned short)(v2.y >> 16));
                acc[i][0] += w3 * bf2f((unsigned short)(v3.x & 0xffff));
                acc[i][1] += w3 * bf2f((unsigned short)(v3.x >> 16));
                acc[i][2] += w3 * bf2f((unsigned short)(v3.y & 0xffff));
                acc[i][3] += w3 * bf2f((unsigned short)(v3.y >> 16));
            }
        }
    }

    // write agg tile (bf16, swizzled)
#pragma unroll
    for (int i = 0; i < 8; ++i) {
        int lr = grp * 8 + i;
        uint2 o;
        o.x = pack2(acc[i][0], acc[i][1]);
        o.y = pack2(acc[i][2], acc[i][3]);
        int colb = l * 8;
        *(uint2*)(lds + lr * STRB + (colb ^ ((lr & 7) << 4))) = o;
    }
    // write self tile
    if (KTILES == 8) {
#pragma unroll
        for (int p = 0; p < 8; ++p) {
            int lr = grp + p * 8;
            int colb = 256 + l * 8;
            *(uint2*)(lds + lr * STRB + (colb ^ ((lr & 7) << 4))) = selfv[p];
        }
    }
    __syncthreads();

    // phase B: MFMA
    const int wave = tid >> 6;
    const int lane = tid & 63;
    const int kg = lane >> 4;
    const int lrA = wave * 16 + (lane & 15);

    f32x4 facc[8];
#pragma unroll
    for (int t = 0; t < 8; ++t) facc[t] = (f32x4){0.f, 0.f, 0.f, 0.f};

#pragma unroll
    for (int kk = 0; kk < KTILES; ++kk) {
        int colb = kk * 64 + kg * 16;
        short8 af = *(const short8*)(lds + lrA * STRB + (colb ^ ((lrA & 7) << 4)));
#pragma unroll
        for (int t = 0; t < 8; ++t) {
            short8 bf = *(const short8*)(Bpack + ((size_t)(t * KTILES + kk) * 64 + lane) * 8);
            facc[t] = __builtin_amdgcn_mfma_f32_16x16x32_bf16(af, bf, facc[t], 0, 0, 0);
        }
    }

    // epilogue
    const int col0 = lane & 15;
    const int crow0 = node0 + wave * 16 + kg * 4;
#pragma unroll
    for (int t = 0; t < 8; ++t) {
        int col = t * 16 + col0;
        float bb = b1[col];
        float b2v = HAS_B2 ? b2[col] : 0.f;
#pragma unroll
        for (int r = 0; r < 4; ++r) {
            int row = crow0 + r;
            if (row < M) {
                float v = facc[t][r] + (float)cnt[row] * bb + b2v;
                if (ADD_BASE) v += bf2f(base[(size_t)row * DD + col]);
                out[(size_t)row * DD + col] = f2bf(v);
            }
        }
    }
}

// ---------------- supervision dot (bf16 inputs, fp32 out) ----------------
__global__ __launch_bounds__(256) void dot_kernel(
    const unsigned short* __restrict__ xa, const unsigned short* __restrict__ xp,
    const int* __restrict__ s0, const int* __restrict__ s1,
    float* __restrict__ out, int E) {
    int g = blockIdx.x * blockDim.x + threadIdx.x;
    int e = g >> 5;
    int l = g & 31;
    if (e >= E) return;
    int a = s0[e], p = s1[e];
    uint2 va = *(const uint2*)(xa + (size_t)a * DD + l * 4);
    uint2 vp = *(const uint2*)(xp + (size_t)p * DD + l * 4);
    float s = bf2f((unsigned short)(va.x & 0xffff)) * bf2f((unsigned short)(vp.x & 0xffff))
            + bf2f((unsigned short)(va.x >> 16)) * bf2f((unsigned short)(vp.x >> 16))
            + bf2f((unsigned short)(va.y & 0xffff)) * bf2f((unsigned short)(vp.y & 0xffff))
            + bf2f((unsigned short)(va.y >> 16)) * bf2f((unsigned short)(vp.y >> 16));
    s += __shfl_xor(s, 1); s += __shfl_xor(s, 2); s += __shfl_xor(s, 4);
    s += __shfl_xor(s, 8); s += __shfl_xor(s, 16);
    if (l == 0) out[e] = s;
}

extern "C" void kernel_launch(void* const* d_in, const int* in_sizes, int n_in,
                              void* d_out, int out_size, void* d_ws, size_t ws_size,
                              hipStream_t stream) {
    const float* xa_in = (const float*)d_in[0];
    const float* xp_in = (const float*)d_in[1];
    const int* eidx = (const int*)d_in[2];
    const int* co = (const int*)d_in[3];
    const int* sup = (const int*)d_in[4];
    const float* W_a2p = (const float*)d_in[5];
    const float* b_a2p = (const float*)d_in[6];
    const float* W_p2a = (const float*)d_in[7];
    const float* b_p2a = (const float*)d_in[8];
    const float* W_aself = (const float*)d_in[9];
    const float* b_aself = (const float*)d_in[10];
    const float* W_pself = (const float*)d_in[11];
    const float* b_pself = (const float*)d_in[12];
    const float* W_co = (const float*)d_in[13];
    const float* b_co = (const float*)d_in[14];

    const int NA = in_sizes[0] / DD;
    const int NP = in_sizes[1] / DD;
    const int E = in_sizes[2] / 2;
    const int Eco = in_sizes[3] / 2;
    const int Esup = in_sizes[4] / 2;
    const int* a_idx = eidx;
    const int* p_idx = eidx + E;
    const int* co_s = co;
    const int* co_d = co + Eco;
    const int* s0 = sup;
    const int* s1 = sup + Esup;

    char* w = (char*)d_ws;
    auto carve = [&](size_t bytes) -> char* {
        char* p = w;
        w += (bytes + 255) & ~(size_t)255;
        return p;
    };
    unsigned short* XA = (unsigned short*)carve((size_t)NA * DD * 2);
    unsigned short* XP = (unsigned short*)carve((size_t)NP * DD * 2);
    unsigned short* P0b = (unsigned short*)carve((size_t)NP * DD * 2);
    unsigned short* P1b = (unsigned short*)carve((size_t)NP * DD * 2);
    unsigned short* A0b = (unsigned short*)carve((size_t)NA * DD * 2);
    unsigned short* A1b = (unsigned short*)carve((size_t)NA * DD * 2);
    int* cntP = (int*)carve((size_t)NP * 4);
    int* rowP = (int*)carve((size_t)NP * 4);
    int* curP = (int*)carve((size_t)NP * 4);
    int* cntA = (int*)carve((size_t)NA * 4);
    int* rowA = (int*)carve((size_t)NA * 4);
    int* curA = (int*)carve((size_t)NA * 4);
    int* cntC = (int*)carve((size_t)NA * 4);
    int* rowC = (int*)carve((size_t)NA * 4);
    int* curC = (int*)carve((size_t)NA * 4);
    int* adjP = (int*)carve((size_t)E * 4);
    int* adjA = (int*)carve((size_t)E * 4);
    int* adjC = (int*)carve((size_t)Eco * 4);
    int* partP = (int*)carve(256 * 4);
    int* partA = (int*)carve(256 * 4);
    int* partC = (int*)carve(256 * 4);
    short* BPp0 = (short*)carve(8 * 8 * 64 * 8 * 2);
    short* BPp1 = (short*)carve(8 * 8 * 64 * 8 * 2);
    short* BPa0 = (short*)carve(8 * 8 * 64 * 8 * 2);
    short* BPa1 = (short*)carve(8 * 8 * 64 * 8 * 2);
    short* BPc0 = (short*)carve(8 * 4 * 64 * 8 * 2);
    short* BPc1 = (short*)carve(8 * 4 * 64 * 8 * 2);

    const int WL = 128 * 128;
    conv_bf16<<<(NA * DD / 4 + 255) / 256, 256, 0, stream>>>(xa_in, XA, NA * DD / 4);
    conv_bf16<<<(NP * DD / 4 + 255) / 256, 256, 0, stream>>>(xp_in, XP, NP * DD / 4);
    pack_w<<<16, 256, 0, stream>>>(W_a2p, W_pself, BPp0, 8);
    pack_w<<<16, 256, 0, stream>>>(W_a2p + WL, W_pself + WL, BPp1, 8);
    pack_w<<<16, 256, 0, stream>>>(W_p2a, W_aself, BPa0, 8);
    pack_w<<<16, 256, 0, stream>>>(W_p2a + WL, W_aself + WL, BPa1, 8);
    pack_w<<<8, 256, 0, stream>>>(W_co, nullptr, BPc0, 4);
    pack_w<<<8, 256, 0, stream>>>(W_co + WL, nullptr, BPc1, 4);

    hipMemsetAsync(cntP, 0, (size_t)NP * 4, stream);
    hipMemsetAsync(cntA, 0, (size_t)NA * 4, stream);
    hipMemsetAsync(cntC, 0, (size_t)NA * 4, stream);
    count_main<<<(E + 255) / 256, 256, 0, stream>>>(a_idx, p_idx, cntP, cntA, E);
    count_co<<<(Eco + 255) / 256, 256, 0, stream>>>(co_d, cntC, Eco);
    const int nbP = (NP + 1023) / 1024;
    const int nbA = (NA + 1023) / 1024;
    scan_local<<<nbP, 256, 0, stream>>>(cntP, rowP, partP, NP);
    scan_partials<<<1, 256, 0, stream>>>(partP, nbP);
    scan_finalize<<<(NP + 255) / 256, 256, 0, stream>>>(rowP, curP, partP, NP);
    scan_local<<<nbA, 256, 0, stream>>>(cntA, rowA, partA, NA);
    scan_partials<<<1, 256, 0, stream>>>(partA, nbA);
    scan_finalize<<<(NA + 255) / 256, 256, 0, stream>>>(rowA, curA, partA, NA);
    scan_local<<<nbA, 256, 0, stream>>>(cntC, rowC, partC, NA);
    scan_partials<<<1, 256, 0, stream>>>(partC, nbA);
    scan_finalize<<<(NA + 255) / 256, 256, 0, stream>>>(rowC, curC, partC, NA);
    fill_main<<<(E + 255) / 256, 256, 0, stream>>>(a_idx, p_idx, curP, curA, adjP, adjA, E);
    fill_co<<<(Eco + 255) / 256, 256, 0, stream>>>(co_s, co_d, curC, adjC, Eco);

    const int blkP = (NP + 63) / 64;
    const int blkA = (NA + 63) / 64;

    // ---- Layer 1 ----
    fused_kernel<8, true, false><<<blkP, 256, 0, stream>>>(XA, XP, nullptr, adjP, rowP, cntP, BPp0, b_a2p, b_pself, P0b, NP);
    fused_kernel<8, true, false><<<blkA, 256, 0, stream>>>(XP, XA, nullptr, adjA, rowA, cntA, BPa0, b_p2a, b_aself, A0b, NA);
    fused_kernel<4, false, true><<<blkA, 256, 0, stream>>>(A0b, nullptr, A0b, adjC, rowC, cntC, BPc0, b_co, nullptr, A1b, NA);

    // ---- Layer 2 ----
    fused_kernel<8, true, false><<<blkP, 256, 0, stream>>>(A1b, P0b, nullptr, adjP, rowP, cntP, BPp1, b_a2p + 128, b_pself + 128, P1b, NP);
    fused_kernel<8, true, false><<<blkA, 256, 0, stream>>>(P0b, A1b, nullptr, adjA, rowA, cntA, BPa1, b_p2a + 128, b_aself + 128, A0b, NA);
    fused_kernel<4, false, true><<<blkA, 256, 0, stream>>>(A0b, nullptr, A0b, adjC, rowC, cntC, BPc1, b_co + 128, nullptr, A1b, NA);

    // ---- output ----
    dot_kernel<<<(Esup * 32 + 255) / 256, 256, 0, stream>>>(A1b, P1b, s0, s1, (float*)d_out, Esup);
}